// Round 5
// baseline (1217.355 us; speedup 1.0000x reference)
//
#include <hip/hip_runtime.h>
#include <cstddef>

// Problem constants (match reference): B=32, D=64, T=8192, K=512
#define B_ 32
#define D_ 64
#define T_ 8192
#define K_ 512

typedef float v2f __attribute__((ext_vector_type(2)));

// ---------------------------------------------------------------------------
// e2[k] = np.sum(emb*emb, -1), numpy pairwise-8 order (n=64), no contraction.
// Written to d_ws; main kernel s_loads it (uniform address, scalar pipe).
// ---------------------------------------------------------------------------
__global__ __launch_bounds__(256) void vq_e2_kernel(const float* __restrict__ emb,
                                                    float* __restrict__ e2) {
#pragma clang fp contract(off)
    int k = blockIdx.x * 256 + threadIdx.x;
    if (k >= K_) return;
    const float* er = emb + k * D_;
    float r[8];
#pragma unroll
    for (int j = 0; j < 8; ++j) r[j] = er[j] * er[j];
#pragma unroll
    for (int i = 8; i < 64; i += 8) {
#pragma unroll
        for (int j = 0; j < 8; ++j) {
            float p = er[i + j] * er[i + j];
            r[j] = r[j] + p;
        }
    }
    e2[k] = ((r[0] + r[1]) + (r[2] + r[3])) + ((r[4] + r[5]) + (r[6] + r[7]));
}

// ---------------------------------------------------------------------------
// TWO threads per (b,t): lanes 2i (h=0) and 2i+1 (h=1).
// Bit-replicates the numpy fp32 pipeline (verified absmax==0 rounds 2-4):
//   xe via npyv AVX512 dot: SIMD lane s in [0,16) accumulates d in
//   {s,s+16,s+32,s+48} with chain fma(a0,b0,fma(a1,b1,fma(a2,b2,fma(a3,b3,0))));
//   reduce tree strides 8/4/2/1; dist = fma(-2,xe,x2) + e2; argmin strict <.
//
// Thread h owns npyv lanes (as v2f accs, global id g): h=0 -> {0,1,4,5},
// h=1 -> {2,3,6,7}. Then s8_x = acc[x]+acc[x+4] is THREAD-LOCAL
// (s8_0=g0+g4, s8_1=g1+g5 on h=0; s8_2,s8_3 on h=1); only the two s8 v2f
// cross the pair (shfl_xor 1). s4/s2/xe/dist/argmin are computed redundantly
// on both threads -- identical bits (fp add is commutative in rounding).
//
// WHY the split (rounds 2-4 evidence): the allocator refuses to keep 64
// x-floats/thread resident (squeezes to 48 VGPRs, remats/AGPR-spills x into
// the K-loop). 32 floats/thread fits its comfort zone. emb rows become two
// 32B-contiguous broadcast VMEM loads per m-step (L1-hot).
// ---------------------------------------------------------------------------
__global__ __launch_bounds__(256, 6) void vq_kernel(const float* __restrict__ x,
                                                    const float* __restrict__ emb,
                                                    const float* __restrict__ e2g,
                                                    float* __restrict__ out) {
    const int h = threadIdx.x & 1;              // half of the lane pair
    const int t = blockIdx.x * 128 + (threadIdx.x >> 1);
    const int b = blockIdx.y;
    const float* xp = x + ((size_t)b * D_) * T_ + t;

    // Thread's d-set: d = 2*(lg&1) + 8*(lg>>1) + 4h + 16m, plus d+1.
    // (h=0: d mod 8 in {0..3}; h=1: d mod 8 in {4..7})
    v2f xl[16];
#pragma unroll
    for (int lg = 0; lg < 4; ++lg) {
#pragma unroll
        for (int m = 0; m < 4; ++m) {
            int d = 2 * (lg & 1) + 8 * (lg >> 1) + 4 * h + 16 * m;
            v2f p;
            p[0] = xp[(size_t)d * T_];
            p[1] = xp[(size_t)(d + 1) * T_];
            xl[lg * 4 + m] = p;
        }
    }
    // Pin x half in VGPRs (opaque -> no remat). 32 VGPRs, well under budget.
#pragma unroll
    for (int j = 0; j < 16; ++j) asm("" : "+v"(xl[j]));

    // ---- x2: numpy pairwise-8. Thread h computes columns j = 4h+j2 (its own
    // d's exactly); combine halves with one shfl. x2 = u0 + u1 bit-exact.
    float x2;
    {
#pragma clang fp contract(off)
        float r[4];
#pragma unroll
        for (int j2 = 0; j2 < 4; ++j2) {
            float v = xl[(j2 >> 1) * 4][j2 & 1];   // i = 0
            r[j2] = v * v;
        }
#pragma unroll
        for (int i = 8; i < 64; i += 8) {
#pragma unroll
            for (int j2 = 0; j2 < 4; ++j2) {
                int idx = (j2 >> 1) * 4 + ((i >> 3) & 1) * 8 + (i >> 4);
                float v = xl[idx][j2 & 1];
                float p = v * v;
                r[j2] = r[j2] + p;
            }
        }
        float u_own = (r[0] + r[1]) + (r[2] + r[3]);
        float u_recv = __shfl_xor(u_own, 1, 64);
        x2 = u_recv + u_own;   // == u0 + u1 on both threads (commutative)
    }

    // ---- K-loop
    float best = 3.4e38f;
    int bi = 0;
    {
#pragma clang fp contract(off)
        for (int k = 0; k < K_; ++k) {
            // emb row: per m, thread needs er[16m+4h .. +3] (accs lg0,lg1) and
            // er[16m+8+4h .. +3] (lg2,lg3). Across the pair each load is one
            // contiguous 32B segment -> cheap broadcast-style VMEM.
            const float4* ebh = (const float4*)(emb + k * D_ + 4 * h);
            float4 ea0 = ebh[0], eb0 = ebh[2];
            float4 ea1 = ebh[4], eb1 = ebh[6];
            float4 ea2 = ebh[8], eb2 = ebh[10];
            float4 ea3 = ebh[12], eb3 = ebh[14];

            // chain: innermost first is m=3, then m=2, m=1, m=0 (npyv order)
            v2f acc[4];
#pragma unroll
            for (int lg = 0; lg < 4; ++lg) {
                v2f e3, e2v, e1, e0, z;
                z[0] = 0.f; z[1] = 0.f;
                const float4& a3 = (lg < 2) ? ea3 : eb3;
                const float4& a2 = (lg < 2) ? ea2 : eb2;
                const float4& a1 = (lg < 2) ? ea1 : eb1;
                const float4& a0 = (lg < 2) ? ea0 : eb0;
                if ((lg & 1) == 0) {
                    e3[0] = a3.x; e3[1] = a3.y;
                    e2v[0] = a2.x; e2v[1] = a2.y;
                    e1[0] = a1.x; e1[1] = a1.y;
                    e0[0] = a0.x; e0[1] = a0.y;
                } else {
                    e3[0] = a3.z; e3[1] = a3.w;
                    e2v[0] = a2.z; e2v[1] = a2.w;
                    e1[0] = a1.z; e1[1] = a1.w;
                    e0[0] = a0.z; e0[1] = a0.w;
                }
                acc[lg] = __builtin_elementwise_fma(xl[lg * 4 + 3], e3, z);
                acc[lg] = __builtin_elementwise_fma(xl[lg * 4 + 2], e2v, acc[lg]);
                acc[lg] = __builtin_elementwise_fma(xl[lg * 4 + 1], e1, acc[lg]);
                acc[lg] = __builtin_elementwise_fma(xl[lg * 4 + 0], e0, acc[lg]);
            }

            // local s8 pair: h=0 -> (s8_0,s8_1); h=1 -> (s8_2,s8_3)
            v2f sA = acc[0] + acc[2];   // g: 0+4 (h=0) / 2+6 (h=1)
            v2f sB = acc[1] + acc[3];   // g: 1+5 (h=0) / 3+7 (h=1)

            // exchange s8 across the pair (bit-exact movement)
            v2f rA, rB;
            rA[0] = __shfl_xor(sA[0], 1, 64);
            rA[1] = __shfl_xor(sA[1], 1, 64);
            rB[0] = __shfl_xor(sB[0], 1, 64);
            rB[1] = __shfl_xor(sB[1], 1, 64);

            // s4_0 = s8_0 + s8_2, s4_1 = s8_1 + s8_3 (commutative -> identical
            // bits on both threads regardless of which operand was local)
            v2f s4_0 = sA + rA;
            v2f s4_1 = sB + rB;
            v2f s2v  = s4_0 + s4_1;
            float xe = s2v[0] + s2v[1];

            float tt   = fmaf(-2.0f, xe, x2);  // == fl(x2 - 2*xe), one rounding
            float dist = tt + e2g[k];          // e2g[k]: uniform -> s_load

            if (dist < best) { best = dist; bi = k; }  // strict <: first index
        }
    }

    // ---- epilogue: each thread writes its own 32 d's. bi identical across
    // the pair. out0 = x + (q - x) elementwise fp32, out1 = q.
    float* o0 = out + ((size_t)b * D_) * T_ + t;
    float* o1 = o0 + (size_t)B_ * D_ * T_;
    {
#pragma clang fp contract(off)
        const float* q = emb + bi * D_;
#pragma unroll
        for (int lg = 0; lg < 4; ++lg) {
#pragma unroll
            for (int m = 0; m < 4; ++m) {
                int d = 2 * (lg & 1) + 8 * (lg >> 1) + 4 * h + 16 * m;
                float2 qp = *(const float2*)(q + d);   // d even -> 8B aligned
                v2f xv = xl[lg * 4 + m];
                float df0 = qp.x - xv[0];
                float df1 = qp.y - xv[1];
                o0[(size_t)d * T_]       = xv[0] + df0;
                o0[(size_t)(d + 1) * T_] = xv[1] + df1;
                o1[(size_t)d * T_]       = qp.x;
                o1[(size_t)(d + 1) * T_] = qp.y;
            }
        }
    }
}

extern "C" void kernel_launch(void* const* d_in, const int* in_sizes, int n_in,
                              void* d_out, int out_size, void* d_ws, size_t ws_size,
                              hipStream_t stream) {
    const float* x   = (const float*)d_in[0];   // [B, D, T] fp32
    const float* emb = (const float*)d_in[1];   // [K, D] fp32
    float* e2  = (float*)d_ws;                  // K floats scratch
    float* out = (float*)d_out;                 // [2, B, D, T] fp32

    vq_e2_kernel<<<dim3(2), dim3(256), 0, stream>>>(emb, e2);
    vq_kernel<<<dim3(T_ / 128, B_), dim3(256), 0, stream>>>(x, emb, e2, out);
}

// Round 6
// 385.607 us; speedup vs baseline: 3.1570x; 3.1570x over previous
//
#include <hip/hip_runtime.h>
#include <cstddef>

// Problem constants (match reference): B=32, D=64, T=8192, K=512
#define B_ 32
#define D_ 64
#define T_ 8192
#define K_ 512

typedef float v2f __attribute__((ext_vector_type(2)));

// ---------------------------------------------------------------------------
// One thread per (b,t). Bit-replicates the numpy fp32 pipeline (verified
// absmax==0 in rounds 2-4):
//   x2  = np.sum(xp*xp, -1)        -> pairwise 8-accumulator block (n=64)
//   e2  = np.sum(emb*emb, -1)      -> same pairwise scheme (precomputed in LDS)
//   xe  = np.einsum('btd,kd->btk') -> npyv AVX512 dot: 16 lanes, 4-deep fused
//                                     FMA chain + 8/4/2/1 pairwise reduce
//   dist = fma(-2, xe, x2) + e2    -> identical to (x2 - 2*xe) + e2 since
//                                     2*xe is exact and fma rounds once
//   argmin: strict <, first index wins (np.argmin tie-break)
//
// ROUND 6 FIX: rounds 2-4 compiled to 48 VGPRs because __launch_bounds__'s
// 2nd arg only sets the register CAP (min waves/EU); the AMDGPU scheduler
// still TARGETS max occupancy (10 waves -> 48-VGPR granule) and its remat
// stage pushes the 64 x-loads back inside the K-loop to get there (grid
// supplies only 4 waves/SIMD, so that occupancy is unusable).
// amdgpu_waves_per_eu(4,4) sets the occupancy TARGET to 4 -> no gain from
// squeezing below 128 VGPRs -> x stays register-resident.
// Round-5 lesson kept: emb row on the SGPR/s_load path (256 B/iter/wave via
// scalar cache), no per-iter cross-lane ops, no per-iter per-lane VMEM.
// ---------------------------------------------------------------------------
__global__ __launch_bounds__(256)
__attribute__((amdgpu_waves_per_eu(4, 4)))
void vq_kernel(const float* __restrict__ x,
               const float* __restrict__ emb,
               float* __restrict__ out) {
    __shared__ float s_e2[K_];

    // ---- e2 precompute into LDS, numpy pairwise-8 order, no FMA contraction
    {
#pragma clang fp contract(off)
        for (int k = threadIdx.x; k < K_; k += 256) {
            const float* er = emb + k * D_;
            float r[8];
#pragma unroll
            for (int j = 0; j < 8; ++j) r[j] = er[j] * er[j];
#pragma unroll
            for (int i = 8; i < 64; i += 8) {
#pragma unroll
                for (int j = 0; j < 8; ++j) {
                    float p = er[i + j] * er[i + j];
                    r[j] = r[j] + p;
                }
            }
            s_e2[k] = ((r[0] + r[1]) + (r[2] + r[3])) + ((r[4] + r[5]) + (r[6] + r[7]));
        }
    }
    __syncthreads();

    const int t = blockIdx.x * 256 + threadIdx.x;
    const int b = blockIdx.y;
    const float* xp = x + ((size_t)b * D_) * T_ + t;

    // ---- load x[b, :, t] into 32 packed v2f regs (coalesced across lanes)
    v2f xr[D_ / 2];
#pragma unroll
    for (int j = 0; j < D_ / 2; ++j) {
        v2f p;
        p[0] = xp[(size_t)(2 * j) * T_];
        p[1] = xp[(size_t)(2 * j + 1) * T_];
        xr[j] = p;
    }
    // Belt-and-braces: opaque to the optimizer -> cannot be rematerialized.
#pragma unroll
    for (int j = 0; j < D_ / 2; ++j) {
        asm volatile("" : "+v"(xr[j]));
    }
#define XD(d) (xr[(d) >> 1][(d) & 1])

    // ---- x2 via numpy pairwise-8 (products first, then sequential adds)
    float x2;
    {
#pragma clang fp contract(off)
        float r[8];
#pragma unroll
        for (int j = 0; j < 8; ++j) r[j] = XD(j) * XD(j);
#pragma unroll
        for (int i = 8; i < 64; i += 8) {
#pragma unroll
            for (int j = 0; j < 8; ++j) {
                float p = XD(i + j) * XD(i + j);
                r[j] = r[j] + p;
            }
        }
        x2 = ((r[0] + r[1]) + (r[2] + r[3])) + ((r[4] + r[5]) + (r[6] + r[7]));
    }

    // ---- K-loop: replicate einsum npyv dot (AVX512: vstep=16, one x4 iter)
    float best = 3.4e38f;
    int bi = 0;
    {
#pragma clang fp contract(off)
        for (int k = 0; k < K_; ++k) {
            const float* er = emb + k * D_;  // wave-uniform -> s_load path

            // acc[j] holds SIMD lanes (2j, 2j+1); lane L accumulates d in
            // {L, L+16, L+32, L+48}: acc = fma(a0,b0, fma(a1,b1, fma(a2,b2, fma(a3,b3, 0))))
            v2f acc[8];
#pragma unroll
            for (int j = 0; j < 8; ++j) {
                int L = 2 * j;
                v2f ev, z;
                z[0] = 0.f; z[1] = 0.f;
                ev[0] = er[48 + L]; ev[1] = er[49 + L];
                acc[j] = __builtin_elementwise_fma(xr[(48 + L) >> 1], ev, z);
                ev[0] = er[32 + L]; ev[1] = er[33 + L];
                acc[j] = __builtin_elementwise_fma(xr[(32 + L) >> 1], ev, acc[j]);
                ev[0] = er[16 + L]; ev[1] = er[17 + L];
                acc[j] = __builtin_elementwise_fma(xr[(16 + L) >> 1], ev, acc[j]);
                ev[0] = er[0 + L];  ev[1] = er[1 + L];
                acc[j] = __builtin_elementwise_fma(xr[(0 + L) >> 1], ev, acc[j]);
            }

            // _mm512_reduce_add_ps tree: strides 8, 4, 2, 1 (pairwise)
            v2f s8_0 = acc[0] + acc[4];
            v2f s8_1 = acc[1] + acc[5];
            v2f s8_2 = acc[2] + acc[6];
            v2f s8_3 = acc[3] + acc[7];
            v2f s4_0 = s8_0 + s8_2;
            v2f s4_1 = s8_1 + s8_3;
            v2f s2   = s4_0 + s4_1;
            float xe = s2[0] + s2[1];

            // fl(x2 - 2*xe) via fma: 2*xe exact, single rounding -> identical
            float tt   = fmaf(-2.0f, xe, x2);
            float dist = tt + s_e2[k];

            if (dist < best) { best = dist; bi = k; }  // strict: first index wins
        }
    }

    // ---- epilogue: out0 = x + (q - x) elementwise fp32, out1 = q
    const float* q = emb + bi * D_;
    float* o0 = out + ((size_t)b * D_) * T_ + t;
    float* o1 = o0 + (size_t)B_ * D_ * T_;
    {
#pragma clang fp contract(off)
#pragma unroll
        for (int d = 0; d < D_; ++d) {
            float qd = q[d];
            float xd = XD(d);
            float diff = qd - xd;
            o0[(size_t)d * T_] = xd + diff;
            o1[(size_t)d * T_] = qd;
        }
    }
#undef XD
}

extern "C" void kernel_launch(void* const* d_in, const int* in_sizes, int n_in,
                              void* d_out, int out_size, void* d_ws, size_t ws_size,
                              hipStream_t stream) {
    const float* x   = (const float*)d_in[0];   // [B, D, T] fp32
    const float* emb = (const float*)d_in[1];   // [K, D] fp32
    float* out = (float*)d_out;                 // [2, B, D, T] fp32

    vq_kernel<<<dim3(T_ / 256, B_), dim3(256), 0, stream>>>(x, emb, out);
}